// Round 10
// baseline (27.300 us; speedup 1.0000x reference)
//
#include <hip/hip_runtime.h>

// PyBlaz 8x8 block DCT + int8 quantization.
// R9 = R8 with the grid-size bug fixed (R8 launched 512 WGs instead of 4096,
// covering only 1/8 of the blocks -- absmax fail from memset'd output).
// Structure: software-pipelined persistent waves. Each wave keeps the R7
// 8-lane/block compute core but loops over 8 batches with depth-1 register
// prefetch: batch i+1's loads issue before batch i's compute, stores drain
// under the next batch's loads.
//
// Input: x (4096 x 4096 fp32). Outputs (concatenated in d_out as float32):
//   [0, 262144)               biggest (512 x 512)
//   [262144, 262144+16777216)  indices as float (512 x 512 x 64)

#define IMG_W 4096
#define NB    512          // blocks per dim
#define NBLK  (NB * NB)    // 262144 total 8x8 blocks
#define WG    64           // one wave
#define ITERS 8            // batches of 8 blocks per wave -> 64 blocks/WG

typedef float f32x4 __attribute__((ext_vector_type(4)));

__global__ __launch_bounds__(WG, 4) void dct_quant_kernel(
    const float* __restrict__ x,
    float* __restrict__ out_big,
    float* __restrict__ out_idx)
{
    // Transpose buffer: 8 blocks, stride 72 dwords (8x8 + 8 pad): the (b,e)
    // write pattern is a 2-way bank alias (free, m136).
    __shared__ __align__(16) float T[8 * 72];     // 2304 B
    __shared__ float Dl[64];                       // D[e][f] table
    __shared__ unsigned int Sg[8 * 18];            // packed int8 staging

    const int l = threadIdx.x;
    const int b = l & 7;       // block-within-batch
    const int g = l >> 3;      // row index: phase1 'e' role, phase2 'g' role

    // ---- Build D table: lane l computes D[e'][f'], (e',f') = (g, b) ----
    // D[e][f] = scale(f) * cos(pi*(2e+1)*f/16); revolutions = (2e+1)*f/32.
    {
        float rev = (float)((2 * g + 1) * b) * (1.0f / 32.0f);
        rev = rev - floorf(rev);                   // v_fract
        float c;
        asm("v_cos_f32 %0, %1" : "=v"(c) : "v"(rev));  // input in revolutions
        const float sc = (b == 0) ? 0.35355339059327373f : 0.5f;
        Dl[g * 8 + b] = sc * c;                    // Dl[e'*8+f']
    }
    __syncthreads();   // single-wave WG -> lgkmcnt-only

    // Per-lane D column for phase 2 (broadcast reads, hoisted out of loop).
    float Dg[8];
#pragma unroll
    for (int e = 0; e < 8; ++e) Dg[e] = Dl[e * 8 + g];

    // Compile-time D literals for the row transform.
    const float s0 = 0.35355339059327373f;
    const float d1 = 0.49039264020161522f;
    const float d2 = 0.46193976625564337f;
    const float d3 = 0.41573480615127262f;
    const float d4 = 0.35355339059327379f;
    const float d5 = 0.27778511650980114f;
    const float d6 = 0.19134171618254492f;
    const float d7 = 0.09754516100806413f;
    const float D[8][8] = {
        { s0,  d1,  d2,  d3,  d4,  d5,  d6,  d7},
        { s0,  d3,  d6, -d7, -d4, -d1, -d2, -d5},
        { s0,  d5, -d6, -d1, -d4,  d7,  d2,  d3},
        { s0,  d7, -d2, -d5,  d4,  d3, -d6, -d1},
        { s0, -d7, -d2,  d5,  d4, -d3, -d6,  d1},
        { s0, -d5, -d6,  d1, -d4, -d7,  d2, -d3},
        { s0, -d3,  d6,  d7, -d4,  d1, -d2,  d5},
        { s0, -d1,  d2, -d3,  d4, -d5,  d6, -d7},
    };

    // WG w owns 64 consecutive blocks [w*64, w*64+64): same block-row bi,
    // 64 consecutive bj -> each lane walks 2KB contiguously along one image
    // row, 64B per iteration. (8 WGs per block-row: 8*64 blocks = 512 = NB.)
    const int wgid = blockIdx.x;
    const int bi   = wgid >> 3;                       // block row (uniform)
    const float* rowbase = x + (size_t)(bi * 8 + g) * IMG_W
                             + (size_t)(wgid & 7) * 512 + (size_t)b * 8;

    // Prologue: issue batch 0's loads.
    float4 a0 = *reinterpret_cast<const float4*>(rowbase);
    float4 a1 = *reinterpret_cast<const float4*>(rowbase + 4);

#pragma unroll
    for (int it = 0; it < ITERS; ++it) {
        // ---- Prefetch batch it+1 BEFORE computing batch it ----
        float4 n0 = a0, n1 = a1;
        if (it + 1 < ITERS) {
            n0 = *reinterpret_cast<const float4*>(rowbase + (it + 1) * 64);
            n1 = *reinterpret_cast<const float4*>(rowbase + (it + 1) * 64 + 4);
        }

        const int gblk0 = wgid * 64 + it * 8;     // first block of this batch

        // ---- Phase 1: row transform, swizzled LDS transpose ----
        const float row[8] = {a0.x, a0.y, a0.z, a0.w, a1.x, a1.y, a1.z, a1.w};
        float* tw = &T[b * 72 + g * 8];
#pragma unroll
        for (int h = 0; h < 8; ++h) {
            float acc = row[0] * D[0][h];
#pragma unroll
            for (int f = 1; f < 8; ++f) acc = fmaf(row[f], D[f][h], acc);
            tw[h ^ g] = acc;
        }

        __syncthreads();

        // ---- Phase 2: column transform. Lane (b,g) computes C[g][0..7]. ----
        float C[8];
#pragma unroll
        for (int h = 0; h < 8; ++h) C[h] = 0.0f;

        const float* tr = &T[b * 72];
#pragma unroll
        for (int e = 0; e < 8; ++e) {
            const float4 c0 = *reinterpret_cast<const float4*>(tr + e * 8);
            const float4 c1 = *reinterpret_cast<const float4*>(tr + e * 8 + 4);
            const float rj[8] = {c0.x, c0.y, c0.z, c0.w, c1.x, c1.y, c1.z, c1.w};
#pragma unroll
            for (int h = 0; h < 8; ++h)
                C[h] = fmaf(Dg[e], rj[h ^ e], C[h]);   // tmp_e[h] = rj[h^e]
        }

        // ---- abs-max: within lane, then across the 8 g-lanes ----
        float m = fabsf(C[0]);
#pragma unroll
        for (int h = 1; h < 8; ++h) m = fmaxf(m, fabsf(C[h]));
        m = fmaxf(m, __shfl_xor(m, 8, 64));
        m = fmaxf(m, __shfl_xor(m, 16, 64));
        m = fmaxf(m, __shfl_xor(m, 32, 64));

        if (g == 0)
            __builtin_nontemporal_store(m, &out_big[gblk0 + b]);

        const float safe = (m == 0.0f) ? 1.0f : m;
        const float inv  = 127.0f / safe;

        // ---- Quantize, pack 8 int8 -> 2 u32, stage in LDS ----
        int q[8];
#pragma unroll
        for (int h = 0; h < 8; ++h) q[h] = (int)rintf(C[h] * inv);
        const unsigned int w0 = (q[0] & 0xff) | ((q[1] & 0xff) << 8) |
                                ((q[2] & 0xff) << 16) | ((unsigned)(q[3] & 0xff) << 24);
        const unsigned int w1 = (q[4] & 0xff) | ((q[5] & 0xff) << 8) |
                                ((q[6] & 0xff) << 16) | ((unsigned)(q[7] & 0xff) << 24);
        Sg[b * 18 + g * 2]     = w0;
        Sg[b * 18 + g * 2 + 1] = w1;

        __syncthreads();

        // ---- Dense copy-out: 8 blocks x 256 B = 2 KB contiguous ----
        f32x4* og = reinterpret_cast<f32x4*>(out_idx + (size_t)gblk0 * 64);
#pragma unroll
        for (int kk = 0; kk < 2; ++kk) {
            const int k = kk * 64 + l;
            const unsigned int w = Sg[(k >> 4) * 18 + (k & 15)];
            f32x4 qv;
            qv.x = (float)(int)(signed char)(w        & 0xff);
            qv.y = (float)(int)(signed char)((w >> 8)  & 0xff);
            qv.z = (float)(int)(signed char)((w >> 16) & 0xff);
            qv.w = (float)(int)(signed char)(w >> 24);
            __builtin_nontemporal_store(qv, &og[k]);
        }

        __syncthreads();   // LDS reuse fence before next batch overwrites T/Sg

        // rotate prefetch registers
        a0 = n0; a1 = n1;
    }
}

extern "C" void kernel_launch(void* const* d_in, const int* in_sizes, int n_in,
                              void* d_out, int out_size, void* d_ws, size_t ws_size,
                              hipStream_t stream) {
    const float* x = (const float*)d_in[0];
    float* out = (float*)d_out;
    float* out_big = out;          // 262144 floats
    float* out_idx = out + NBLK;   // 16777216 floats

    // Each WG covers WG/8 * ITERS = 64 blocks -> grid = NBLK/64 = 4096.
    dct_quant_kernel<<<NBLK / 64, WG, 0, stream>>>(x, out_big, out_idx);
}